// Round 11
// baseline (2527.428 us; speedup 1.0000x reference)
//
#include <hip/hip_runtime.h>
#include <stdint.h>

typedef __bf16 bf16;
typedef bf16 bf16x8 __attribute__((ext_vector_type(8)));
typedef bf16 bf16x4 __attribute__((ext_vector_type(4)));
typedef float f32x4 __attribute__((ext_vector_type(4)));
typedef uint32_t u32;
typedef uint8_t u8;

#define B_TOT 16384
#define SWG 8
#define NWGS (B_TOT / SWG)   // 2048

__device__ __forceinline__ f32x4 mfma32(bf16x8 a, bf16x8 b, f32x4 c) {
  return __builtin_amdgcn_mfma_f32_16x16x32_bf16(a, b, c, 0, 0, 0);
}

// ---- slot barriers: counted vmcnt keeps in-flight stages alive across barrier ----
__device__ __forceinline__ void bar_lg() {
  __builtin_amdgcn_sched_barrier(0);
  asm volatile("s_waitcnt lgkmcnt(0)" ::: "memory");
  __builtin_amdgcn_s_barrier();
  __builtin_amdgcn_sched_barrier(0);
}
__device__ __forceinline__ void bar_v0() {
  __builtin_amdgcn_sched_barrier(0);
  asm volatile("s_waitcnt vmcnt(0) lgkmcnt(0)" ::: "memory");
  __builtin_amdgcn_s_barrier();
  __builtin_amdgcn_sched_barrier(0);
}
__device__ __forceinline__ void bar_v2() {
  __builtin_amdgcn_sched_barrier(0);
  asm volatile("s_waitcnt vmcnt(2) lgkmcnt(0)" ::: "memory");
  __builtin_amdgcn_s_barrier();
  __builtin_amdgcn_sched_barrier(0);
}
__device__ __forceinline__ void bar_v4() {
  __builtin_amdgcn_sched_barrier(0);
  asm volatile("s_waitcnt vmcnt(4) lgkmcnt(0)" ::: "memory");
  __builtin_amdgcn_s_barrier();
  __builtin_amdgcn_sched_barrier(0);
}

// Stage a full [128 rows x 256 bytes] weight tile (32KB) into LDS.
// 1024 threads -> 2 global_load_lds(16B)/thread. Swizzle on GLOBAL source
// (byte ^ ((row&7)<<4)); LDS image linear; reads apply same XOR (involution).
__device__ __forceinline__ void stage32(const u8* __restrict__ src, int rowstride, int colbase,
                                        u8* dst, int tid) {
  __builtin_amdgcn_sched_barrier(0);
#pragma unroll
  for (int rr = 0; rr < 2; ++rr) {
    u32 o = (u32)(rr * 1024 + tid) * 16u;
    u32 row = o >> 8, cb = o & 0xF0u;
    const u8* s = src + (size_t)row * (size_t)rowstride + (size_t)colbase
                      + (size_t)(cb ^ ((row & 7u) << 4));
    __builtin_amdgcn_global_load_lds((const __attribute__((address_space(1))) u32*)s,
                                     (__attribute__((address_space(3))) u32*)(dst + o),
                                     16, 0, 0);
  }
}

// read one weight fragment (A or B; identical layouts) from a staged 32KB tile
__device__ __forceinline__ bf16x8 wread(const u8* Wb, int row, u32 koff) {
  return *(const bf16x8*)(Wb + (u32)(row * 256) + (koff ^ (((u32)row & 7u) << 4)));
}

// scalar store into swizzled row-major [32 rows][128 cols] bf16 ACTIVATION tile
__device__ __forceinline__ void st_row(u8* base, int row, int col, bf16 v) {
  *(bf16*)(base + (u32)(row * 256) + (u32)((2 * col) ^ ((row & 15) << 4))) = v;
}

// A-fragments (2 samples, full K=128) from swizzled row-major activation tile
__device__ __forceinline__ void loadA_rm(const u8* R, int g, int c, bf16x8 a[2][4]) {
  const u32 sw = (u32)c << 4;
#pragma unroll
  for (int mt = 0; mt < 2; ++mt)
#pragma unroll
    for (int ks = 0; ks < 4; ++ks)
      a[mt][ks] = *(const bf16x8*)(R + (u32)((mt * 16 + c) * 256)
                                     + (((u32)(ks * 64 + g * 16)) ^ sw));
}

// pack 4 f32 -> two u32 of bf16 pairs
__device__ __forceinline__ void pack4(const f32x4 v, u32& w0, u32& w1) {
  union { bf16 h[2]; u32 u; } t0, t1;
  t0.h[0] = (bf16)v[0]; t0.h[1] = (bf16)v[1];
  t1.h[0] = (bf16)v[2]; t1.h[1] = (bf16)v[3];
  w0 = t0.u; w1 = t1.u;
}

// C-frag of 16x16 block T -> A/B-frag of T^T (r6-verified); zeros for g>=2
__device__ __forceinline__ bf16x8 Rfrag(u32 w0, u32 w1, int g, int c) {
  int s0 = 32 * g + c;
  int s1 = 32 * g + 16 + c;
  u32 a0 = (u32)__shfl((int)w0, s0);
  u32 a1 = (u32)__shfl((int)w1, s0);
  u32 a2 = (u32)__shfl((int)w0, s1);
  u32 a3 = (u32)__shfl((int)w1, s1);
  union { u32 u[4]; bf16x8 v; } r;
  bool ok = (g < 2);
  r.u[0] = ok ? a0 : 0u; r.u[1] = ok ? a1 : 0u;
  r.u[2] = ok ? a2 : 0u; r.u[3] = ok ? a3 : 0u;
  return r.v;
}

__device__ __forceinline__ void ln_part(const f32x4 x[2][2], float sS[2][4], float sS2[2][4]) {
#pragma unroll
  for (int mt = 0; mt < 2; ++mt) {
    f32x4 a = x[mt][0] + x[mt][1];
    f32x4 b = x[mt][0] * x[mt][0] + x[mt][1] * x[mt][1];
#pragma unroll
    for (int r = 0; r < 4; ++r) {
      float s = a[r], s2 = b[r];
#pragma unroll
      for (int off = 1; off < 16; off <<= 1) { s += __shfl_xor(s, off); s2 += __shfl_xor(s2, off); }
      sS[mt][r] = s; sS2[mt][r] = s2;
    }
  }
}

__global__ void __launch_bounds__(1024, 1)
bot_main(const int* __restrict__ adj,
         const float* __restrict__ embB, const float* __restrict__ posE,
         const float* __restrict__ pbq, const float* __restrict__ pbk,
         const float* __restrict__ pbv, const float* __restrict__ pbo,
         const float* __restrict__ l1g, const float* __restrict__ l1b,
         const float* __restrict__ l2g, const float* __restrict__ l2b,
         const float* __restrict__ pb1, const float* __restrict__ pb2,
         const bf16* __restrict__ feats, const bf16* __restrict__ embWT,
         const bf16* __restrict__ wqT, const bf16* __restrict__ wkT,
         const bf16* __restrict__ wvT, const bf16* __restrict__ woT,
         const bf16* __restrict__ w1T, const bf16* __restrict__ w2T,
         float* __restrict__ out) {
  __shared__ u8 smem[163840];   // 64KB act (4 pairs x (Th+Tq)) + 3x32KB weights
  const int tid = threadIdx.x;
  const int w = tid >> 6, lane = tid & 63, g = lane >> 4, c = lane & 15;
  const int p = w >> 2, qd = w & 3;   // pair (0..3), quadrant (0..3)
  const int S0 = blockIdx.x * SWG;

  u8* pairb = smem + p * 16384;
  u8* Th = pairb;            // h -> h2
  u8* Tq = pairb + 8192;     // O -> U; LN scratch at base in dead windows
  u8* WA = smem + 65536;     // 3 x 32KB weight FIFO; stage #s -> (WB,WC,WA)[s%3]
  u8* WB = smem + 98304;
  u8* WC = smem + 131072;
  float* scr = (float*)Tq;   // [32 rows][4 quadrants][2]

  // transposed mask for S^T layout: lane(g,c),r -> (key m=4g+r, query n=c)
  float maskT[4];
#pragma unroll
  for (int r = 0; r < 4; ++r) {
    int m = 4 * g + r;
    maskT[r] = (adj[c * 16 + m] != 0 || c == m) ? 0.f : -1e9f;
  }

  // ---------------- embed (WG-cooperative; x0 = [8 samples][2048] = 64KB) ----------------
  {
    float* x0 = (float*)smem;
    bf16x8 af[2];
#pragma unroll
    for (int ks = 0; ks < 2; ++ks)
      af[ks] = *(const bf16x8*)(feats + (size_t)(S0 + (c & 7)) * 64 + ks * 32 + g * 8);
    f32x4 ea[8] = {};
#pragma unroll
    for (int nt = 0; nt < 8; ++nt)
#pragma unroll
      for (int ks = 0; ks < 2; ++ks) {
        bf16x8 bw = *(const bf16x8*)(embWT + (size_t)(w * 128 + nt * 16 + c) * 64 + ks * 32 + g * 8);
        ea[nt] = mfma32(af[ks], bw, ea[nt]);
      }
    if (g < 2) {   // rows 0..7 = samples 0..7 (rows 8..15 duplicate via c&7)
#pragma unroll
      for (int nt = 0; nt < 8; ++nt)
#pragma unroll
        for (int r = 0; r < 4; ++r)
          x0[(4 * g + r) * 2048 + w * 128 + nt * 16 + c] = ea[nt][r];
    }
  }
  __syncthreads();

  f32x4 x[2][2];
  {
    const float* x0 = (const float*)smem;
#pragma unroll
    for (int nt = 0; nt < 2; ++nt)
#pragma unroll
      for (int r = 0; r < 4; ++r) {
        int n = 4 * g + r, d = qd * 32 + nt * 16 + c;
        float eb = embB[n * 128 + d] + posE[n * 128 + d];
#pragma unroll
        for (int mt = 0; mt < 2; ++mt)
          x[mt][nt][r] = x0[(2 * p + mt) * 2048 + n * 128 + d] + eb;
      }
  }
  __syncthreads();

  // ---------------- layers: 20-slot schedule, 3x32KB FIFO, lag-2 staging ----------------
#pragma unroll 1
  for (int l = 0; l < 4; ++l) {
    const u8* Wq_l = (const u8*)(wqT + (size_t)l * 16384);
    const u8* Wk_l = (const u8*)(wkT + (size_t)l * 16384);
    const u8* Wv_l = (const u8*)(wvT + (size_t)l * 16384);
    const u8* Wo_l = (const u8*)(woT + (size_t)l * 16384);
    const u8* W1_l = (const u8*)(w1T + (size_t)l * 65536);
    const u8* W2_l = (const u8*)(w2T + (size_t)l * 65536);

    float sS[2][4], sS2[2][4], mean[2][4], rstd[2][4];
    const f32x4 zz = {0.f, 0.f, 0.f, 0.f};

    // s0: LN1 partials -> scr | issue Wq->WA
    ln_part(x, sS, sS2);
    if (c == 0) {
#pragma unroll
      for (int mt = 0; mt < 2; ++mt)
#pragma unroll
        for (int r = 0; r < 4; ++r) {
          int row = mt * 16 + 4 * g + r;
          scr[(row * 4 + qd) * 2 + 0] = sS[mt][r];
          scr[(row * 4 + qd) * 2 + 1] = sS2[mt][r];
        }
    }
    stage32(Wq_l, 256, 0, WA, tid);
    bar_lg();

    // s1: LN1 combine + h -> Th | issue Wk->WB
#pragma unroll
    for (int mt = 0; mt < 2; ++mt)
#pragma unroll
      for (int r = 0; r < 4; ++r) {
        int row = mt * 16 + 4 * g + r;
        float s = 0.f, s2 = 0.f;
#pragma unroll
        for (int qq = 0; qq < 4; ++qq) {
          s += scr[(row * 4 + qq) * 2 + 0];
          s2 += scr[(row * 4 + qq) * 2 + 1];
        }
        float mu = s * (1.f / 128.f);
        float va = s2 * (1.f / 128.f) - mu * mu;
        mean[mt][r] = mu; rstd[mt][r] = rsqrtf(va + 1e-5f);
      }
#pragma unroll
    for (int nt = 0; nt < 2; ++nt) {
      int col = qd * 32 + nt * 16 + c;
      float gg = l1g[l * 128 + col], bb = l1b[l * 128 + col];
#pragma unroll
      for (int mt = 0; mt < 2; ++mt)
#pragma unroll
        for (int r = 0; r < 4; ++r)
          st_row(Th, mt * 16 + 4 * g + r, col,
                 (bf16)((x[mt][nt][r] - mean[mt][r]) * rstd[mt][r] * gg + bb));
    }
    stage32(Wk_l, 256, 0, WB, tid);
    bar_v2();

    bf16x8 Ah[2][4], Qb[2][2], Ka[2][2];
    // s2: loadA(h); SWAPPED Q^T-gemm (heads 2qd,2qd+1) -> Rfrag -> Qb | issue Wv->WC
    loadA_rm(Th, g, c, Ah);
#pragma unroll
    for (int hh = 0; hh < 2; ++hh) {
      int gh = qd * 2 + hh;
      f32x4 qa[2] = {zz, zz};
#pragma unroll
      for (int ks = 0; ks < 4; ++ks) {
        bf16x8 wf = wread(WA, gh * 16 + c, (u32)(ks * 64 + g * 16));
        qa[0] = mfma32(wf, Ah[0][ks], qa[0]);   // D rows = out-dims, cols = nodes
        qa[1] = mfma32(wf, Ah[1][ks], qa[1]);
      }
      const float* bql = pbq + l * 128 + gh * 16 + 4 * g;
#pragma unroll
      for (int mt = 0; mt < 2; ++mt) {
        f32x4 v;
#pragma unroll
        for (int r = 0; r < 4; ++r) v[r] = qa[mt][r] + bql[r];
        u32 w0, w1; pack4(v, w0, w1);
        Qb[hh][mt] = Rfrag(w0, w1, g, c);       // lane c: Q[node c][8 dims]
      }
    }
    stage32(Wv_l, 256, 0, WC, tid);
    bar_v2();

    // s3: SWAPPED K^T-gemm -> Rfrag -> Ka | issue Wo->WA
#pragma unroll
    for (int hh = 0; hh < 2; ++hh) {
      int gh = qd * 2 + hh;
      f32x4 ka[2] = {zz, zz};
#pragma unroll
      for (int ks = 0; ks < 4; ++ks) {
        bf16x8 wf = wread(WB, gh * 16 + c, (u32)(ks * 64 + g * 16));
        ka[0] = mfma32(wf, Ah[0][ks], ka[0]);
        ka[1] = mfma32(wf, Ah[1][ks], ka[1]);
      }
      const float* bkl = pbk + l * 128 + gh * 16 + 4 * g;
#pragma unroll
      for (int mt = 0; mt < 2; ++mt) {
        f32x4 v;
#pragma unroll
        for (int r = 0; r < 4; ++r) v[r] = ka[mt][r] + bkl[r];
        u32 w0, w1; pack4(v, w0, w1);
        Ka[hh][mt] = Rfrag(w0, w1, g, c);       // lane c: K[node c][8 dims]
      }
    }
    stage32(Wo_l, 256, 0, WA, tid);
    bar_v2();

    // s4: V-gemm (normal) + full per-head in-register ATTENTION; O -> Tq | issue W1c0->WB
    {
      const u32 swa = (u32)c << 4;
#pragma unroll
      for (int hh = 0; hh < 2; ++hh) {
        int gh = qd * 2 + hh;
        f32x4 va[2] = {zz, zz};
#pragma unroll
        for (int ks = 0; ks < 4; ++ks) {
          bf16x8 wf = wread(WC, gh * 16 + c, (u32)(ks * 64 + g * 16));
          va[0] = mfma32(Ah[0][ks], wf, va[0]);  // rows = nodes, cols = dims
          va[1] = mfma32(Ah[1][ks], wf, va[1]);
        }
        float bvv = pbv[l * 128 + gh * 16 + c];
#pragma unroll
        for (int mt = 0; mt < 2; ++mt) {
          f32x4 v;
#pragma unroll
          for (int r = 0; r < 4; ++r) v[r] = va[mt][r] + bvv;
          u32 w0, w1; pack4(v, w0, w1);
          bf16x8 Vf = Rfrag(w0, w1, g, c);       // A-frag of V^T
          f32x4 st = mfma32(Ka[hh][mt], Qb[hh][mt], zz);   // S^T
          float pr[4];
#pragma unroll
          for (int r = 0; r < 4; ++r) pr[r] = st[r] * 0.25f + maskT[r];
          float mx = fmaxf(fmaxf(pr[0], pr[1]), fmaxf(pr[2], pr[3]));
          mx = fmaxf(mx, __shfl_xor(mx, 16));
          mx = fmaxf(mx, __shfl_xor(mx, 32));
          float sm = 0.f;
#pragma unroll
          for (int r = 0; r < 4; ++r) { pr[r] = __expf(pr[r] - mx); sm += pr[r]; }
          sm += __shfl_xor(sm, 16);
          sm += __shfl_xor(sm, 32);
          float pinv = __fdividef(1.f, sm);
          f32x4 pv;
#pragma unroll
          for (int r = 0; r < 4; ++r) pv[r] = pr[r] * pinv;
          pack4(pv, w0, w1);
          bf16x8 Pf = Rfrag(w0, w1, g, c);       // B-frag: P[query][keys]
          f32x4 oo = mfma32(Vf, Pf, zz);         // O^T: rows dims, cols nodes
          pack4(oo, w0, w1);
          bf16x8 Of = Rfrag(w0, w1, g, c);       // lane c: O[node c][8 dims]
          if (g < 2)
            *(bf16x8*)(Tq + (u32)((mt * 16 + c) * 256)
                          + (((u32)(gh * 32 + g * 16)) ^ swa)) = Of;
        }
      }
    }
    stage32(W1_l, 256, 0, WB, tid);
    bar_lg();

    // s5: loadA(O)
    loadA_rm(Tq, g, c, Ah);
    bar_v2();

    // s6: O-proj (WA, normal) into x; +bo; LN2 partials -> scr | issue W2c0->WC
#pragma unroll
    for (int nt = 0; nt < 2; ++nt) {
      int col = qd * 32 + nt * 16 + c;
#pragma unroll
      for (int ks = 0; ks < 4; ++ks) {
        bf16x8 wf = wread(WA, col, (u32)(ks * 64 + g * 16));
        x[0][nt] = mfma32(Ah[0][ks], wf, x[0][nt]);
        x[1][nt] = mfma32(Ah[1][ks], wf, x[1][nt]);
      }
      float bb = pbo[l * 128 + col];
#pragma unroll
      for (int mt = 0; mt < 2; ++mt)
#pragma unroll
        for (int r = 0; r < 4; ++r) x[mt][nt][r] += bb;
    }
    ln_part(x, sS, sS2);
    if (c == 0) {
#pragma unroll
      for (int mt = 0; mt < 2; ++mt)
#pragma unroll
        for (int r = 0; r < 4; ++r) {
          int row = mt * 16 + 4 * g + r;
          scr[(row * 4 + qd) * 2 + 0] = sS[mt][r];
          scr[(row * 4 + qd) * 2 + 1] = sS2[mt][r];
        }
    }
    stage32(W2_l, 1024, 0, WC, tid);
    bar_lg();

    // s7: LN2 combine + h2 -> Th | issue W1c1->WA
#pragma unroll
    for (int mt = 0; mt < 2; ++mt)
#pragma unroll
      for (int r = 0; r < 4; ++r) {
        int row = mt * 16 + 4 * g + r;
        float s = 0.f, s2 = 0.f;
#pragma unroll
        for (int qq = 0; qq < 4; ++qq) {
          s += scr[(row * 4 + qq) * 2 + 0];
          s2 += scr[(row * 4 + qq) * 2 + 1];
        }
        float mu = s * (1.f / 128.f);
        float va = s2 * (1.f / 128.f) - mu * mu;
        mean[mt][r] = mu; rstd[mt][r] = rsqrtf(va + 1e-5f);
      }
#pragma unroll
    for (int nt = 0; nt < 2; ++nt) {
      int col = qd * 32 + nt * 16 + c;
      float gg = l2g[l * 128 + col], bb = l2b[l * 128 + col];
#pragma unroll
      for (int mt = 0; mt < 2; ++mt)
#pragma unroll
        for (int r = 0; r < 4; ++r)
          st_row(Th, mt * 16 + 4 * g + r, col,
                 (bf16)((x[mt][nt][r] - mean[mt][r]) * rstd[mt][r] * gg + bb));
    }
    stage32(W1_l + 32768, 256, 0, WA, tid);
    bar_v4();

    // ---------------- FFN: per fc {U-slot, capture-slot, Y-slot} ----------------
    // stage order: W1c0,W2c0,W1c1,W2c1,... -> buffer (WB,WC,WA)[stage# % 3]
    bf16x8 Ah2[2][4], Au[2][4];
#pragma unroll 1
    for (int fc = 0; fc < 4; ++fc) {
      int s1i = (2 * fc) % 3, s2i = (2 * fc + 1) % 3;
      u8* w1b = (s1i == 0) ? WB : ((s1i == 1) ? WC : WA);
      u8* w2b = (s2i == 0) ? WB : ((s2i == 1) ? WC : WA);
      // sU: (fc==0: loadA h2); U-gemm (w1b) + relu epi -> Tq | issue W1c2/W1c3
      if (fc == 0) loadA_rm(Th, g, c, Ah2);
#pragma unroll
      for (int nt = 0; nt < 2; ++nt) {
        int col = qd * 32 + nt * 16 + c;
        f32x4 u2[2] = {zz, zz};
#pragma unroll
        for (int ks = 0; ks < 4; ++ks) {
          bf16x8 wf = wread(w1b, col, (u32)(ks * 64 + g * 16));
          u2[0] = mfma32(Ah2[0][ks], wf, u2[0]);
          u2[1] = mfma32(Ah2[1][ks], wf, u2[1]);
        }
        float bb = pb1[l * 512 + fc * 128 + col];
#pragma unroll
        for (int mt = 0; mt < 2; ++mt)
#pragma unroll
          for (int r = 0; r < 4; ++r)
            st_row(Tq, mt * 16 + 4 * g + r, col, (bf16)fmaxf(u2[mt][r] + bb, 0.f));
      }
      if (fc == 1) stage32(W1_l + 2 * 32768, 256, 0, WC, tid);   // stage#4 -> WC
      if (fc == 2) stage32(W1_l + 3 * 32768, 256, 0, WB, tid);   // stage#6 -> WB
      bar_lg();
      // sC: capture U
      loadA_rm(Tq, g, c, Au);
      if (fc < 3) bar_v2(); else bar_v0();
      // sY: Y-gemm (w2b) into x | issue W2c(fc+1) -> w1b (fc<3)
#pragma unroll
      for (int nt = 0; nt < 2; ++nt) {
        int col = qd * 32 + nt * 16 + c;
#pragma unroll
        for (int ks = 0; ks < 4; ++ks) {
          bf16x8 wf = wread(w2b, col, (u32)(ks * 64 + g * 16));
          x[0][nt] = mfma32(Au[0][ks], wf, x[0][nt]);
          x[1][nt] = mfma32(Au[1][ks], wf, x[1][nt]);
        }
      }
      if (fc < 3) { stage32(W2_l, 1024, (fc + 1) * 256, w1b, tid); bar_v2(); }
    }
#pragma unroll
    for (int nt = 0; nt < 2; ++nt) {
      float bb = pb2[l * 128 + qd * 32 + nt * 16 + c];
#pragma unroll
      for (int mt = 0; mt < 2; ++mt)
#pragma unroll
        for (int r = 0; r < 4; ++r) x[mt][nt][r] += bb;
    }
  }

  // ---------------- output: LDS bounce ([8 samples][8KB], activation area) ----------------
  bar_lg();
#pragma unroll
  for (int nt = 0; nt < 2; ++nt) {
    int col = qd * 32 + nt * 16 + c;
#pragma unroll
    for (int mt = 0; mt < 2; ++mt)
      *(f32x4*)(smem + (2 * p + mt) * 8192 + col * 64 + g * 16) = x[mt][nt];
  }
  bar_lg();
  {
    const int sm = S0 + (w >> 1);     // 2 waves per sample
    const int hf = w & 1;
    const u8* src = smem + (w >> 1) * 8192;
#pragma unroll
    for (int it = 0; it < 4; ++it) {
      int n = hf * 8 + it * 2 + (lane >> 5);
      int slot = lane & 31;
      f32x4 v;
#pragma unroll
      for (int e = 0; e < 4; ++e)
        v[e] = *(const float*)(src + (u32)((slot * 4 + e) * 64 + n * 4));
      __builtin_nontemporal_store(v, (f32x4*)(out + (size_t)sm * 2048 + n * 128 + slot * 4));
    }
  }
}

// ---------------- prep kernels ----------------
__global__ void prep_feats_k(const float* __restrict__ pos, const float* __restrict__ vel,
                             bf16* __restrict__ feats) {
  int i = blockIdx.x * 256 + threadIdx.x;
  if (i >= B_TOT * 64) return;
  int b = i >> 6, k = i & 63;
  float v = (k < 32) ? pos[b * 32 + k] : vel[b * 32 + (k - 32)];
  feats[i] = (bf16)v;
}

// dst[m][cc][rr] = (bf16) src[m][rr][cc]; src is [mats][R][C] fp32
__global__ void prep_tr_k(const float* __restrict__ src, bf16* __restrict__ dst,
                          int R, int C, int total) {
  int i = blockIdx.x * 256 + threadIdx.x;
  if (i >= total) return;
  int rc = R * C;
  int m = i / rc, rem = i % rc;
  int cc = rem / R, rr = rem % R;
  dst[i] = (bf16)src[(size_t)m * rc + rr * C + cc];
}

extern "C" void kernel_launch(void* const* d_in, const int* in_sizes, int n_in,
                              void* d_out, int out_size, void* d_ws, size_t ws_size,
                              hipStream_t stream) {
  const float* jp  = (const float*)d_in[0];
  const float* jv  = (const float*)d_in[1];
  const int*   adj = (const int*)d_in[2];
  const float* eW  = (const float*)d_in[3];
  const float* eB  = (const float*)d_in[4];
  const float* pE  = (const float*)d_in[5];
  const float* Wq  = (const float*)d_in[6];  const float* bq = (const float*)d_in[7];
  const float* Wk  = (const float*)d_in[8];  const float* bk = (const float*)d_in[9];
  const float* Wv  = (const float*)d_in[10]; const float* bv = (const float*)d_in[11];
  const float* Wo  = (const float*)d_in[12]; const float* bo = (const float*)d_in[13];
  const float* g1  = (const float*)d_in[14]; const float* be1 = (const float*)d_in[15];
  const float* g2  = (const float*)d_in[16]; const float* be2 = (const float*)d_in[17];
  const float* W1  = (const float*)d_in[18]; const float* b1 = (const float*)d_in[19];
  const float* W2  = (const float*)d_in[20]; const float* b2 = (const float*)d_in[21];

  bf16* ws    = (bf16*)d_ws;
  bf16* feats = ws;                    // 1048576
  bf16* embWT = ws + 1048576;          // 131072  [16*128 outcol][64 in]
  bf16* wqT   = embWT + 131072;        // 65536   [4][128 out][128 in]
  bf16* wkT   = wqT + 65536;
  bf16* wvT   = wkT + 65536;
  bf16* woT   = wvT + 65536;
  bf16* w1T   = woT + 65536;           // 262144  [4][512 f][128 in]
  bf16* w2T   = w1T + 262144;          // 262144  [4][128 out][512 f]

  prep_feats_k<<<(B_TOT * 64 + 255) / 256, 256, 0, stream>>>(jp, jv, feats);
  prep_tr_k<<<512, 256, 0, stream>>>(eW, embWT, 64, 128, 131072);
  prep_tr_k<<<256, 256, 0, stream>>>(Wq, wqT, 128, 128, 65536);
  prep_tr_k<<<256, 256, 0, stream>>>(Wk, wkT, 128, 128, 65536);
  prep_tr_k<<<256, 256, 0, stream>>>(Wv, wvT, 128, 128, 65536);
  prep_tr_k<<<256, 256, 0, stream>>>(Wo, woT, 128, 128, 65536);
  prep_tr_k<<<1024, 256, 0, stream>>>(W1, w1T, 128, 512, 262144);
  prep_tr_k<<<1024, 256, 0, stream>>>(W2, w2T, 512, 128, 262144);

  bot_main<<<NWGS, 1024, 0, stream>>>(adj, eB, pE, bq, bk, bv, bo,
                                      g1, be1, g2, be2, b1, b2,
                                      feats, embWT, wqT, wkT, wvT, woT, w1T, w2T,
                                      (float*)d_out);
}

// Round 12
// 1374.246 us; speedup vs baseline: 1.8391x; 1.8391x over previous
//
#include <hip/hip_runtime.h>
#include <stdint.h>

typedef __bf16 bf16;
typedef bf16 bf16x8 __attribute__((ext_vector_type(8)));
typedef bf16 bf16x4 __attribute__((ext_vector_type(4)));
typedef float f32x4 __attribute__((ext_vector_type(4)));
typedef uint32_t u32;
typedef uint8_t u8;

#define B_TOT 16384
#define SWG 8
#define NWGS (B_TOT / SWG)   // 2048

__device__ __forceinline__ f32x4 mfma32(bf16x8 a, bf16x8 b, f32x4 c) {
  return __builtin_amdgcn_mfma_f32_16x16x32_bf16(a, b, c, 0, 0, 0);
}

// ---- slot barriers (counted vmcnt keeps newest stages in flight) ----
__device__ __forceinline__ void bar_lg() {
  __builtin_amdgcn_sched_barrier(0);
  asm volatile("s_waitcnt lgkmcnt(0)" ::: "memory");
  __builtin_amdgcn_s_barrier();
  __builtin_amdgcn_sched_barrier(0);
}
__device__ __forceinline__ void bar_v0() {
  __builtin_amdgcn_sched_barrier(0);
  asm volatile("s_waitcnt vmcnt(0) lgkmcnt(0)" ::: "memory");
  __builtin_amdgcn_s_barrier();
  __builtin_amdgcn_sched_barrier(0);
}
__device__ __forceinline__ void bar_v2() {   // keep newest stage (2 loads)
  __builtin_amdgcn_sched_barrier(0);
  asm volatile("s_waitcnt vmcnt(2) lgkmcnt(0)" ::: "memory");
  __builtin_amdgcn_s_barrier();
  __builtin_amdgcn_sched_barrier(0);
}
__device__ __forceinline__ void bar_v4() {   // keep newest 2 stages (4 loads)
  __builtin_amdgcn_sched_barrier(0);
  asm volatile("s_waitcnt vmcnt(4) lgkmcnt(0)" ::: "memory");
  __builtin_amdgcn_s_barrier();
  __builtin_amdgcn_sched_barrier(0);
}

// Stage one [128 rows x 128 bytes] weight K-half (16KB) into LDS (512 thr ->
// 2 loads/thread). Swizzle on GLOBAL source; LDS image linear-swizzled.
__device__ __forceinline__ void stage16(const u8* __restrict__ src, int rowstride, int colbase,
                                        u8* dst, int tid) {
  __builtin_amdgcn_sched_barrier(0);
#pragma unroll
  for (int rr = 0; rr < 2; ++rr) {
    u32 o = (u32)(rr * 512 + tid) * 16u;
    u32 row = o >> 7, cb = o & 0x7Fu;
    const u8* s = src + (size_t)row * (size_t)rowstride + (size_t)colbase
                      + (size_t)(cb ^ ((row & 7u) << 4));
    __builtin_amdgcn_global_load_lds((const __attribute__((address_space(1))) u32*)s,
                                     (__attribute__((address_space(3))) u32*)(dst + o),
                                     16, 0, 0);
  }
}

// weight fragment from a 16KB half-stage ([128 rows][128B], swizzled)
__device__ __forceinline__ bf16x8 wread16(const u8* Wb, int row, u32 koff) {
  return *(const bf16x8*)(Wb + (u32)(row * 128) + (koff ^ (((u32)row & 7u) << 4)));
}

// scalar store into swizzled row-major [32 rows][128 cols] bf16 ACTIVATION tile
__device__ __forceinline__ void st_row(u8* base, int row, int col, bf16 v) {
  *(bf16*)(base + (u32)(row * 256) + (u32)((2 * col) ^ ((row & 15) << 4))) = v;
}

// A-fragments (2 samples, full K=128) from swizzled row-major activation tile
__device__ __forceinline__ void loadA_rm(const u8* R, int g, int c, bf16x8 a[2][4]) {
  const u32 sw = (u32)c << 4;
#pragma unroll
  for (int mt = 0; mt < 2; ++mt)
#pragma unroll
    for (int ks = 0; ks < 4; ++ks)
      a[mt][ks] = *(const bf16x8*)(R + (u32)((mt * 16 + c) * 256)
                                     + (((u32)(ks * 64 + g * 16)) ^ sw));
}

// acc[2][4] += A-half @ W-half (normal orientation; W rows = outcols)
__device__ __forceinline__ void gemm_half(const u8* Wb, int khalf, const bf16x8 a[2][4],
                                          f32x4 acc[2][4], int nh, int g, int c) {
#pragma unroll
  for (int ksl = 0; ksl < 2; ++ksl) {
    int ks = khalf * 2 + ksl;
#pragma unroll
    for (int nt = 0; nt < 4; ++nt) {
      bf16x8 b = wread16(Wb, nh * 64 + nt * 16 + c, (u32)(ksl * 64 + g * 16));
      acc[0][nt] = mfma32(a[0][ks], b, acc[0][nt]);
      acc[1][nt] = mfma32(a[1][ks], b, acc[1][nt]);
    }
  }
}

// pack 4 f32 -> two u32 of bf16 pairs
__device__ __forceinline__ void pack4(const f32x4 v, u32& w0, u32& w1) {
  union { bf16 h[2]; u32 u; } t0, t1;
  t0.h[0] = (bf16)v[0]; t0.h[1] = (bf16)v[1];
  t1.h[0] = (bf16)v[2]; t1.h[1] = (bf16)v[3];
  w0 = t0.u; w1 = t1.u;
}

// C-frag of 16x16 block T -> A/B-frag of T^T (r6/r11-verified); zeros for g>=2
__device__ __forceinline__ bf16x8 Rfrag(u32 w0, u32 w1, int g, int c) {
  int s0 = 32 * g + c;
  int s1 = 32 * g + 16 + c;
  u32 a0 = (u32)__shfl((int)w0, s0);
  u32 a1 = (u32)__shfl((int)w1, s0);
  u32 a2 = (u32)__shfl((int)w0, s1);
  u32 a3 = (u32)__shfl((int)w1, s1);
  union { u32 u[4]; bf16x8 v; } r;
  bool ok = (g < 2);
  r.u[0] = ok ? a0 : 0u; r.u[1] = ok ? a1 : 0u;
  r.u[2] = ok ? a2 : 0u; r.u[3] = ok ? a3 : 0u;
  return r.v;
}

__device__ __forceinline__ void ln_part(const f32x4 x[2][4], float sS[2][4], float sS2[2][4]) {
#pragma unroll
  for (int mt = 0; mt < 2; ++mt) {
    f32x4 a = {0.f, 0.f, 0.f, 0.f}, b = {0.f, 0.f, 0.f, 0.f};
#pragma unroll
    for (int nt = 0; nt < 4; ++nt) { a += x[mt][nt]; b += x[mt][nt] * x[mt][nt]; }
#pragma unroll
    for (int r = 0; r < 4; ++r) {
      float s = a[r], s2 = b[r];
#pragma unroll
      for (int off = 1; off < 16; off <<= 1) { s += __shfl_xor(s, off); s2 += __shfl_xor(s2, off); }
      sS[mt][r] = s; sS2[mt][r] = s2;
    }
  }
}

__global__ void __launch_bounds__(512, 2)
bot_main(const int* __restrict__ adj,
         const float* __restrict__ embB, const float* __restrict__ posE,
         const float* __restrict__ pbq, const float* __restrict__ pbk,
         const float* __restrict__ pbv, const float* __restrict__ pbo,
         const float* __restrict__ l1g, const float* __restrict__ l1b,
         const float* __restrict__ l2g, const float* __restrict__ l2b,
         const float* __restrict__ pb1, const float* __restrict__ pb2,
         const bf16* __restrict__ feats, const bf16* __restrict__ embWT,
         const bf16* __restrict__ wqT, const bf16* __restrict__ wkT,
         const bf16* __restrict__ wvT, const bf16* __restrict__ woT,
         const bf16* __restrict__ w1T, const bf16* __restrict__ w2T,
         float* __restrict__ out) {
  __shared__ u8 smem[131072];
  const int tid = threadIdx.x;
  const int w = tid >> 6, lane = tid & 63, g = lane >> 4, c = lane & 15;
  const int p = w >> 1, nh = w & 1;   // pair (0..3), N-half
  const int S0 = blockIdx.x * SWG;

  u8* pairb = smem + p * 16384;
  u8* RA = pairb;            // h -> h2
  u8* Rq = pairb + 8192;     // O -> U; scr at base in dead windows
  u8* WB0 = smem + 65536;    // 4 x 16KB weight buffers
  u8* WB1 = smem + 81920;
  u8* WB2 = smem + 98304;
  u8* WB3 = smem + 114688;
  float* scr = (float*)Rq;

  // transposed mask for S^T layout: lane(g,c),r -> (key m=4g+r, query n=c)
  float maskT[4];
#pragma unroll
  for (int r = 0; r < 4; ++r) {
    int m = 4 * g + r;
    maskT[r] = (adj[c * 16 + m] != 0 || c == m) ? 0.f : -1e9f;
  }

  // ---------------- embed (WG-cooperative, transient x0 over act area) ----------------
  {
    float* x0 = (float*)smem;  // [8 samples][2048] = 64KB
    bf16x8 af[2];
#pragma unroll
    for (int ks = 0; ks < 2; ++ks)
      af[ks] = *(const bf16x8*)(feats + (size_t)(S0 + (c & 7)) * 64 + ks * 32 + g * 8);
    f32x4 ea[16] = {};
#pragma unroll
    for (int nt = 0; nt < 16; ++nt)
#pragma unroll
      for (int ks = 0; ks < 2; ++ks) {
        bf16x8 bw = *(const bf16x8*)(embWT + (size_t)(w * 256 + nt * 16 + c) * 64 + ks * 32 + g * 8);
        ea[nt] = mfma32(af[ks], bw, ea[nt]);
      }
    if (g < 2) {
#pragma unroll
      for (int nt = 0; nt < 16; ++nt)
#pragma unroll
        for (int r = 0; r < 4; ++r)
          x0[(4 * g + r) * 2048 + w * 256 + nt * 16 + c] = ea[nt][r];
    }
  }
  __syncthreads();

  f32x4 x[2][4];
  {
    const float* x0 = (const float*)smem;
#pragma unroll
    for (int nt = 0; nt < 4; ++nt)
#pragma unroll
      for (int r = 0; r < 4; ++r) {
        int n = 4 * g + r, d = nh * 64 + nt * 16 + c;
        float eb = embB[n * 128 + d] + posE[n * 128 + d];
#pragma unroll
        for (int mt = 0; mt < 2; ++mt)
          x[mt][nt][r] = x0[(2 * p + mt) * 2048 + n * 128 + d] + eb;
      }
  }
  __syncthreads();

  bf16x8 Ah[2][4], Ah2[2][4], Au[2][4];

  // ---------------- layers: 27-slot schedule ----------------
#pragma unroll 1
  for (int l = 0; l < 4; ++l) {
    const u8* Wq_l = (const u8*)(wqT + (size_t)l * 16384);
    const u8* Wk_l = (const u8*)(wkT + (size_t)l * 16384);
    const u8* Wv_l = (const u8*)(wvT + (size_t)l * 16384);
    const u8* Wo_l = (const u8*)(woT + (size_t)l * 16384);
    const u8* W1_l = (const u8*)(w1T + (size_t)l * 65536);
    const u8* W2_l = (const u8*)(w2T + (size_t)l * 65536);

    float sS[2][4], sS2[2][4], mean[2][4], rstd[2][4];
    const f32x4 zz = {0.f, 0.f, 0.f, 0.f};

    // s0: LN1 partials -> scr (Rq base, dead window) | stage Wq0->B0
    ln_part(x, sS, sS2);
    if (c == 0) {
#pragma unroll
      for (int mt = 0; mt < 2; ++mt)
#pragma unroll
        for (int r = 0; r < 4; ++r) {
          int row = mt * 16 + 4 * g + r;
          scr[(row * 2 + nh) * 2 + 0] = sS[mt][r];
          scr[(row * 2 + nh) * 2 + 1] = sS2[mt][r];
        }
    }
    stage16(Wq_l, 256, 0, WB0, tid);
    bar_lg();

    // s1: LN1 combine + h -> RA | stage Wq1->B1
#pragma unroll
    for (int mt = 0; mt < 2; ++mt)
#pragma unroll
      for (int r = 0; r < 4; ++r) {
        int row = mt * 16 + 4 * g + r;
        float s = sS[mt][r] + scr[(row * 2 + (1 - nh)) * 2 + 0];
        float s2 = sS2[mt][r] + scr[(row * 2 + (1 - nh)) * 2 + 1];
        float mu = s * (1.f / 128.f);
        float va = s2 * (1.f / 128.f) - mu * mu;
        mean[mt][r] = mu; rstd[mt][r] = rsqrtf(va + 1e-5f);
      }
#pragma unroll
    for (int nt = 0; nt < 4; ++nt) {
      int col = nh * 64 + nt * 16 + c;
      float gg = l1g[l * 128 + col], bb = l1b[l * 128 + col];
#pragma unroll
      for (int mt = 0; mt < 2; ++mt)
#pragma unroll
        for (int r = 0; r < 4; ++r)
          st_row(RA, mt * 16 + 4 * g + r, col,
                 (bf16)((x[mt][nt][r] - mean[mt][r]) * rstd[mt][r] * gg + bb));
    }
    stage16(Wq_l, 256, 128, WB1, tid);
    bar_v2();

    bf16x8 Qb[4][2], Ka[4][2], Vf[2][4];
    {
      f32x4 qacc[4][2];
      // s2: loadA(h)->Ah; SWAPPED Q^T half0 (B0) | stage Wk0->B2
      loadA_rm(RA, g, c, Ah);
#pragma unroll
      for (int hh = 0; hh < 4; ++hh) {
        int gh = nh * 4 + hh;
#pragma unroll
        for (int mt = 0; mt < 2; ++mt) qacc[hh][mt] = zz;
#pragma unroll
        for (int ksl = 0; ksl < 2; ++ksl) {
          bf16x8 wf = wread16(WB0, gh * 16 + c, (u32)(ksl * 64 + g * 16));
          qacc[hh][0] = mfma32(wf, Ah[0][ksl], qacc[hh][0]);
          qacc[hh][1] = mfma32(wf, Ah[1][ksl], qacc[hh][1]);
        }
      }
      stage16(Wk_l, 256, 0, WB2, tid);
      bar_v2();

      // s3: Q^T half1 (B1) -> +bias -> Rfrag -> Qb | stage Wk1->B3
#pragma unroll
      for (int hh = 0; hh < 4; ++hh) {
        int gh = nh * 4 + hh;
#pragma unroll
        for (int ksl = 0; ksl < 2; ++ksl) {
          bf16x8 wf = wread16(WB1, gh * 16 + c, (u32)(ksl * 64 + g * 16));
          qacc[hh][0] = mfma32(wf, Ah[0][2 + ksl], qacc[hh][0]);
          qacc[hh][1] = mfma32(wf, Ah[1][2 + ksl], qacc[hh][1]);
        }
        const float* bql = pbq + l * 128 + gh * 16 + 4 * g;
#pragma unroll
        for (int mt = 0; mt < 2; ++mt) {
          f32x4 v;
#pragma unroll
          for (int r = 0; r < 4; ++r) v[r] = qacc[hh][mt][r] + bql[r];
          u32 w0, w1; pack4(v, w0, w1);
          Qb[hh][mt] = Rfrag(w0, w1, g, c);
        }
      }
      stage16(Wk_l, 256, 128, WB3, tid);
      bar_v2();

      // s4: SWAPPED K^T half0 (B2) | stage Wv0->B0
#pragma unroll
      for (int hh = 0; hh < 4; ++hh) {
        int gh = nh * 4 + hh;
#pragma unroll
        for (int mt = 0; mt < 2; ++mt) qacc[hh][mt] = zz;
#pragma unroll
        for (int ksl = 0; ksl < 2; ++ksl) {
          bf16x8 wf = wread16(WB2, gh * 16 + c, (u32)(ksl * 64 + g * 16));
          qacc[hh][0] = mfma32(wf, Ah[0][ksl], qacc[hh][0]);
          qacc[hh][1] = mfma32(wf, Ah[1][ksl], qacc[hh][1]);
        }
      }
      stage16(Wv_l, 256, 0, WB0, tid);
      bar_v2();

      // s5: K^T half1 (B3) -> +bias -> Rfrag -> Ka | stage Wv1->B1
#pragma unroll
      for (int hh = 0; hh < 4; ++hh) {
        int gh = nh * 4 + hh;
#pragma unroll
        for (int ksl = 0; ksl < 2; ++ksl) {
          bf16x8 wf = wread16(WB3, gh * 16 + c, (u32)(ksl * 64 + g * 16));
          qacc[hh][0] = mfma32(wf, Ah[0][2 + ksl], qacc[hh][0]);
          qacc[hh][1] = mfma32(wf, Ah[1][2 + ksl], qacc[hh][1]);
        }
        const float* bkl = pbk + l * 128 + gh * 16 + 4 * g;
#pragma unroll
        for (int mt = 0; mt < 2; ++mt) {
          f32x4 v;
#pragma unroll
          for (int r = 0; r < 4; ++r) v[r] = qacc[hh][mt][r] + bkl[r];
          u32 w0, w1; pack4(v, w0, w1);
          Ka[hh][mt] = Rfrag(w0, w1, g, c);
        }
      }
      stage16(Wv_l, 256, 128, WB1, tid);
      bar_v2();
    }

    f32x4 acc[2][4];
    // s6: V-gemm half0 (B0, normal) | stage Wo0->B2
#pragma unroll
    for (int mt = 0; mt < 2; ++mt)
#pragma unroll
      for (int nt = 0; nt < 4; ++nt) acc[mt][nt] = zz;
    gemm_half(WB0, 0, Ah, acc, nh, g, c);
    stage16(Wo_l, 256, 0, WB2, tid);
    bar_v2();

    // s7: V half1 (B1) -> Vf; ATTENTION fully in-reg; O -> Rq | stage Wo1->B3
    gemm_half(WB1, 1, Ah, acc, nh, g, c);
#pragma unroll
    for (int nt = 0; nt < 4; ++nt) {
      float bb = pbv[l * 128 + nh * 64 + nt * 16 + c];
#pragma unroll
      for (int mt = 0; mt < 2; ++mt) {
        f32x4 v;
#pragma unroll
        for (int r = 0; r < 4; ++r) v[r] = acc[mt][nt][r] + bb;
        u32 w0, w1; pack4(v, w0, w1);
        Vf[mt][nt] = Rfrag(w0, w1, g, c);
      }
    }
    {
      const u32 swa = (u32)c << 4;
#pragma unroll
      for (int hh = 0; hh < 4; ++hh) {
        const int gh = nh * 4 + hh;
#pragma unroll
        for (int mt = 0; mt < 2; ++mt) {
          f32x4 st = mfma32(Ka[hh][mt], Qb[hh][mt], zz);   // S^T
          float pr[4];
#pragma unroll
          for (int r = 0; r < 4; ++r) pr[r] = st[r] * 0.25f + maskT[r];
          float mx = fmaxf(fmaxf(pr[0], pr[1]), fmaxf(pr[2], pr[3]));
          mx = fmaxf(mx, __shfl_xor(mx, 16));
          mx = fmaxf(mx, __shfl_xor(mx, 32));
          float sm = 0.f;
#pragma unroll
          for (int r = 0; r < 4; ++r) { pr[r] = __expf(pr[r] - mx); sm += pr[r]; }
          sm += __shfl_xor(sm, 16);
          sm += __shfl_xor(sm, 32);
          float pinv = __fdividef(1.f, sm);
          f32x4 pv;
#pragma unroll
          for (int r = 0; r < 4; ++r) pv[r] = pr[r] * pinv;
          u32 w0, w1; pack4(pv, w0, w1);
          bf16x8 Pf = Rfrag(w0, w1, g, c);
          f32x4 oo = mfma32(Vf[mt][hh], Pf, zz);           // O^T
          pack4(oo, w0, w1);
          bf16x8 Of = Rfrag(w0, w1, g, c);
          if (g < 2)
            *(bf16x8*)(Rq + (u32)((mt * 16 + c) * 256)
                          + (((u32)(gh * 32 + g * 16)) ^ swa)) = Of;
        }
      }
    }
    stage16(Wo_l, 256, 128, WB3, tid);
    bar_v2();

    // s8: loadA(O); O-proj half0 (B2) into x | stage W1c0-0->B0
    loadA_rm(Rq, g, c, Ah);
    gemm_half(WB2, 0, Ah, x, nh, g, c);
    stage16(W1_l, 256, 0, WB0, tid);
    bar_v2();

    // s9: O-proj half1 (B3) + bo; LN2 partials -> scr | stage W1c0-1->B1
    gemm_half(WB3, 1, Ah, x, nh, g, c);
#pragma unroll
    for (int nt = 0; nt < 4; ++nt) {
      float bb = pbo[l * 128 + nh * 64 + nt * 16 + c];
#pragma unroll
      for (int mt = 0; mt < 2; ++mt)
#pragma unroll
        for (int r = 0; r < 4; ++r) x[mt][nt][r] += bb;
    }
    ln_part(x, sS, sS2);
    if (c == 0) {
#pragma unroll
      for (int mt = 0; mt < 2; ++mt)
#pragma unroll
        for (int r = 0; r < 4; ++r) {
          int row = mt * 16 + 4 * g + r;
          scr[(row * 2 + nh) * 2 + 0] = sS[mt][r];
          scr[(row * 2 + nh) * 2 + 1] = sS2[mt][r];
        }
    }
    stage16(W1_l, 256, 128, WB1, tid);
    bar_lg();

    // s10: LN2 combine + h2 -> RA | stage W2c0-0->B2
#pragma unroll
    for (int mt = 0; mt < 2; ++mt)
#pragma unroll
      for (int r = 0; r < 4; ++r) {
        int row = mt * 16 + 4 * g + r;
        float s = sS[mt][r] + scr[(row * 2 + (1 - nh)) * 2 + 0];
        float s2 = sS2[mt][r] + scr[(row * 2 + (1 - nh)) * 2 + 1];
        float mu = s * (1.f / 128.f);
        float va = s2 * (1.f / 128.f) - mu * mu;
        mean[mt][r] = mu; rstd[mt][r] = rsqrtf(va + 1e-5f);
      }
#pragma unroll
    for (int nt = 0; nt < 4; ++nt) {
      int col = nh * 64 + nt * 16 + c;
      float gg = l2g[l * 128 + col], bb = l2b[l * 128 + col];
#pragma unroll
      for (int mt = 0; mt < 2; ++mt)
#pragma unroll
        for (int r = 0; r < 4; ++r)
          st_row(RA, mt * 16 + 4 * g + r, col,
                 (bf16)((x[mt][nt][r] - mean[mt][r]) * rstd[mt][r] * gg + bb));
    }
    stage16(W2_l, 1024, 0, WB2, tid);
    bar_v4();

    // ---------------- FFN: 4 slots per fc, lag-3, bar_v4 steady ----------------
#pragma unroll 1
    for (int fc = 0; fc < 4; ++fc) {
      f32x4 uacc[2][4];
#pragma unroll
      for (int mt = 0; mt < 2; ++mt)
#pragma unroll
        for (int nt = 0; nt < 4; ++nt) uacc[mt][nt] = zz;
      // sU0: (fc==0: loadA h2); U half0 (B0) | stage W2c(fc)-1 -> B3
      if (fc == 0) loadA_rm(RA, g, c, Ah2);
      gemm_half(WB0, 0, Ah2, uacc, nh, g, c);
      stage16(W2_l, 1024, fc * 256 + 128, WB3, tid);
      bar_v4();
      // sU1: U half1 (B1) + relu epi -> Rq | stage W1c(fc+1)-0 -> B0
      gemm_half(WB1, 1, Ah2, uacc, nh, g, c);
#pragma unroll
      for (int nt = 0; nt < 4; ++nt) {
        int col = nh * 64 + nt * 16 + c;
        float bb = pb1[l * 512 + fc * 128 + col];
#pragma unroll
        for (int mt = 0; mt < 2; ++mt)
#pragma unroll
          for (int r = 0; r < 4; ++r)
            st_row(Rq, mt * 16 + 4 * g + r, col, (bf16)fmaxf(uacc[mt][nt][r] + bb, 0.f));
      }
      if (fc < 3) { stage16(W1_l + (fc + 1) * 32768, 256, 0, WB0, tid); bar_v4(); }
      else bar_v2();
      // sY0: loadA(U); Y half0 (B2) into x | stage W1c(fc+1)-1 -> B1
      loadA_rm(Rq, g, c, Au);
      gemm_half(WB2, 0, Au, x, nh, g, c);
      if (fc < 3) { stage16(W1_l + (fc + 1) * 32768, 256, 128, WB1, tid); bar_v4(); }
      else bar_v0();
      // sY1: Y half1 (B3) into x | stage W2c(fc+1)-0 -> B2
      gemm_half(WB3, 1, Au, x, nh, g, c);
      if (fc < 3) { stage16(W2_l, 1024, (fc + 1) * 256, WB2, tid); bar_v4(); }
      else {
#pragma unroll
        for (int nt = 0; nt < 4; ++nt) {
          float bb = pb2[l * 128 + nh * 64 + nt * 16 + c];
#pragma unroll
          for (int mt = 0; mt < 2; ++mt)
#pragma unroll
            for (int r = 0; r < 4; ++r) x[mt][nt][r] += bb;
        }
        bar_lg();
      }
    }
  }

  // ---------------- output: LDS bounce -> coalesced nontemporal fp32 stores ----------------
#pragma unroll
  for (int nt = 0; nt < 4; ++nt) {
    int col = nh * 64 + nt * 16 + c;
#pragma unroll
    for (int mt = 0; mt < 2; ++mt)
      *(f32x4*)(pairb + mt * 8192 + col * 64 + g * 16) = x[mt][nt];
  }
  bar_lg();
  {
    const int smp = S0 + 2 * p + nh;
    const u8* src = pairb + nh * 8192;
#pragma unroll
    for (int it = 0; it < 8; ++it) {
      int n = it * 2 + (lane >> 5);
      int slot = lane & 31;
      f32x4 v;
#pragma unroll
      for (int e = 0; e < 4; ++e)
        v[e] = *(const float*)(src + (u32)((slot * 4 + e) * 64 + n * 4));
      __builtin_nontemporal_store(v, (f32x4*)(out + (size_t)smp * 2048 + n * 128 + slot * 4));
    }
  }
}

// ---------------- prep kernels ----------------
__global__ void prep_feats_k(const float* __restrict__ pos, const float* __restrict__ vel,
                             bf16* __restrict__ feats) {
  int i = blockIdx.x * 256 + threadIdx.x;
  if (i >= B_TOT * 64) return;
  int b = i >> 6, k = i & 63;
  float v = (k < 32) ? pos[b * 32 + k] : vel[b * 32 + (k - 32)];
  feats[i] = (bf16)v;
}

// dst[m][cc][rr] = (bf16) src[m][rr][cc]; src is [mats][R][C] fp32
__global__ void prep_tr_k(const float* __restrict__ src, bf16* __restrict__ dst,
                          int R, int C, int total) {
  int i = blockIdx.x * 256 + threadIdx.x;
  if (i >= total) return;
  int rc = R * C;
  int m = i / rc, rem = i % rc;
  int cc = rem / R, rr = rem % R;
  dst[i] = (bf16)src[(size_t)m * rc + rr * C + cc];
}

extern "C" void kernel_launch(void* const* d_in, const int* in_sizes, int n_in,
                              void* d_out, int out_size, void* d_ws, size_t ws_size,
                              hipStream_t stream) {
  const float* jp  = (const float*)d_in[0];
  const float* jv  = (const float*)d_in[1];
  const int*   adj = (const int*)d_in[2];
  const float* eW  = (const float*)d_in[3];
  const float* eB  = (const float*)d_in[4];
  const float* pE  = (const float*)d_in[5];
  const float* Wq  = (const float*)d_in[6];  const float* bq = (const float*)d_in[7];
  const float* Wk  = (const float*)d_in[8];  const float* bk = (const float*)d_in[9];
  const float* Wv  = (const float*)d_in[10]; const float* bv = (const float*)d_in[11];
  const float* Wo  = (const float*)d_in[12]; const float* bo = (const float*)d_in[13];
  const float* g1  = (const float*)d_in[14]; const float* be1 = (const float*)d_in[15];
  const float* g2  = (const float*)d_in[16]; const float* be2 = (const float*)d_in[17];
  const float* W1  = (const float*)d_in[18]; const float* b1 = (const float*)d_in[19];
  const float* W2  = (const float*)d_in[20]; const float* b2 = (const float*)d_in[21];

  bf16* ws    = (bf16*)d_ws;
  bf16* feats = ws;                    // 1048576
  bf16* embWT = ws + 1048576;          // 131072  [16*128 outcol][64 in]
  bf16* wqT   = embWT + 131072;        // 65536   [4][128 out][128 in]
  bf16* wkT   = wqT + 65536;
  bf16* wvT   = wkT + 65536;
  bf16* woT   = wvT + 65536;
  bf16* w1T   = woT + 65536;           // 262144  [4][512 f][128 in]
  bf16* w2T   = w1T + 262144;          // 262144  [4][128 out][512 f]

  prep_feats_k<<<(B_TOT * 64 + 255) / 256, 256, 0, stream>>>(jp, jv, feats);
  prep_tr_k<<<512, 256, 0, stream>>>(eW, embWT, 64, 128, 131072);
  prep_tr_k<<<256, 256, 0, stream>>>(Wq, wqT, 128, 128, 65536);
  prep_tr_k<<<256, 256, 0, stream>>>(Wk, wkT, 128, 128, 65536);
  prep_tr_k<<<256, 256, 0, stream>>>(Wv, wvT, 128, 128, 65536);
  prep_tr_k<<<256, 256, 0, stream>>>(Wo, woT, 128, 128, 65536);
  prep_tr_k<<<1024, 256, 0, stream>>>(W1, w1T, 128, 512, 262144);
  prep_tr_k<<<1024, 256, 0, stream>>>(W2, w2T, 512, 128, 262144);

  bot_main<<<NWGS, 512, 0, stream>>>(adj, eB, pE, bq, bk, bv, bo,
                                     g1, be1, g2, be2, b1, b2,
                                     feats, embWT, wqT, wkT, wvT, woT, w1T, w2T,
                                     (float*)d_out);
}

// Round 13
// 1035.631 us; speedup vs baseline: 2.4405x; 1.3270x over previous
//
#include <hip/hip_runtime.h>
#include <stdint.h>

typedef __bf16 bf16;
typedef bf16 bf16x8 __attribute__((ext_vector_type(8)));
typedef bf16 bf16x4 __attribute__((ext_vector_type(4)));
typedef float f32x4 __attribute__((ext_vector_type(4)));
typedef uint32_t u32;
typedef uint8_t u8;

#define B_TOT 16384
#define SWG 8
#define NWGS (B_TOT / SWG)   // 2048

__device__ __forceinline__ f32x4 mfma32(bf16x8 a, bf16x8 b, f32x4 c) {
  return __builtin_amdgcn_mfma_f32_16x16x32_bf16(a, b, c, 0, 0, 0);
}
__device__ __forceinline__ bf16x8 zero8() {
  bf16x8 v;
#pragma unroll
  for (int j = 0; j < 8; j++) v[j] = (bf16)0.f;
  return v;
}

// ---- slot barriers ----
__device__ __forceinline__ void bar_lg() {
  __builtin_amdgcn_sched_barrier(0);
  asm volatile("s_waitcnt lgkmcnt(0)" ::: "memory");
  __builtin_amdgcn_s_barrier();
  __builtin_amdgcn_sched_barrier(0);
}
__device__ __forceinline__ void bar_v0() {
  __builtin_amdgcn_sched_barrier(0);
  asm volatile("s_waitcnt vmcnt(0) lgkmcnt(0)" ::: "memory");
  __builtin_amdgcn_s_barrier();
  __builtin_amdgcn_sched_barrier(0);
}

// Stage a full [128 rows x 256 bytes] weight tile (32KB) into LDS.
// 512 threads -> 4 global_load_lds(16B)/thread. Swizzle on GLOBAL source
// (byte ^ ((row&7)<<4)); LDS image linear; reads apply the same XOR.
// Issued at slot START so latency hides under the slot's compute (T14).
__device__ __forceinline__ void stage32(const u8* __restrict__ src, int rowstride, int colbase,
                                        u8* dst, int tid) {
  __builtin_amdgcn_sched_barrier(0);
#pragma unroll
  for (int rr = 0; rr < 4; ++rr) {
    u32 o = (u32)(rr * 512 + tid) * 16u;
    u32 row = o >> 8, cb = o & 0xF0u;
    const u8* s = src + (size_t)row * (size_t)rowstride + (size_t)colbase
                      + (size_t)(cb ^ ((row & 7u) << 4));
    __builtin_amdgcn_global_load_lds((const __attribute__((address_space(1))) u32*)s,
                                     (__attribute__((address_space(3))) u32*)(dst + o),
                                     16, 0, 0);
  }
  __builtin_amdgcn_sched_barrier(0);
}

// weight fragment from a 32KB full stage ([128 rows][256B], swizzled)
__device__ __forceinline__ bf16x8 wread32(const u8* Wb, int row, u32 koff) {
  return *(const bf16x8*)(Wb + (u32)(row * 256) + (koff ^ (((u32)row & 7u) << 4)));
}

// scalar store into swizzled row-major [32 rows][128 cols] bf16 ACTIVATION tile
__device__ __forceinline__ void st_row(u8* base, int row, int col, bf16 v) {
  *(bf16*)(base + (u32)(row * 256) + (u32)((2 * col) ^ ((row & 15) << 4))) = v;
}

// A-fragments (2 samples, full K=128) from swizzled row-major activation tile
__device__ __forceinline__ void loadA_rm(const u8* R, int g, int c, bf16x8 a[2][4]) {
  const u32 sw = (u32)c << 4;
#pragma unroll
  for (int mt = 0; mt < 2; ++mt)
#pragma unroll
    for (int ks = 0; ks < 4; ++ks)
      a[mt][ks] = *(const bf16x8*)(R + (u32)((mt * 16 + c) * 256)
                                     + (((u32)(ks * 64 + g * 16)) ^ sw));
}

// acc[2][4] += A (full K) @ W (full 32KB tile; rows = outcols)
__device__ __forceinline__ void gemm_full(const u8* Wb, const bf16x8 a[2][4],
                                          f32x4 acc[2][4], int nh, int g, int c) {
#pragma unroll
  for (int ks = 0; ks < 4; ++ks)
#pragma unroll
    for (int nt = 0; nt < 4; ++nt) {
      bf16x8 b = wread32(Wb, nh * 64 + nt * 16 + c, (u32)(ks * 64 + g * 16));
      acc[0][nt] = mfma32(a[0][ks], b, acc[0][nt]);
      acc[1][nt] = mfma32(a[1][ks], b, acc[1][nt]);
    }
}

// C-fragment epilogue -> swizzled row-major tile, scalar stores (r6-verified)
template <bool RELU>
__device__ __forceinline__ void epi_rm(const f32x4 acc[2][4], const float* __restrict__ bias,
                                       u8* Rdst, int nh, int g, int c) {
#pragma unroll
  for (int nt = 0; nt < 4; ++nt) {
    int col = nh * 64 + nt * 16 + c;
    float bb = bias[col];
#pragma unroll
    for (int mt = 0; mt < 2; ++mt)
#pragma unroll
      for (int r = 0; r < 4; ++r) {
        float v = acc[mt][nt][r] + bb;
        if (RELU) v = fmaxf(v, 0.f);
        st_row(Rdst, mt * 16 + 4 * g + r, col, (bf16)v);
      }
  }
}

// pack 4 f32 -> two u32 of bf16 pairs
__device__ __forceinline__ void pack4(const f32x4 v, u32& w0, u32& w1) {
  union { bf16 h[2]; u32 u; } t0, t1;
  t0.h[0] = (bf16)v[0]; t0.h[1] = (bf16)v[1];
  t1.h[0] = (bf16)v[2]; t1.h[1] = (bf16)v[3];
  w0 = t0.u; w1 = t1.u;
}

// C-frag of 16x16 block T -> A/B-frag of T^T (r6-verified); zeros for g>=2
__device__ __forceinline__ bf16x8 Rfrag(u32 w0, u32 w1, int g, int c) {
  int s0 = 32 * g + c;
  int s1 = 32 * g + 16 + c;
  u32 a0 = (u32)__shfl((int)w0, s0);
  u32 a1 = (u32)__shfl((int)w1, s0);
  u32 a2 = (u32)__shfl((int)w0, s1);
  u32 a3 = (u32)__shfl((int)w1, s1);
  union { u32 u[4]; bf16x8 v; } r;
  bool ok = (g < 2);
  r.u[0] = ok ? a0 : 0u; r.u[1] = ok ? a1 : 0u;
  r.u[2] = ok ? a2 : 0u; r.u[3] = ok ? a3 : 0u;
  return r.v;
}

__device__ __forceinline__ void ln_part(const f32x4 x[2][4], float sS[2][4], float sS2[2][4]) {
#pragma unroll
  for (int mt = 0; mt < 2; ++mt) {
    f32x4 a = {0.f, 0.f, 0.f, 0.f}, b = {0.f, 0.f, 0.f, 0.f};
#pragma unroll
    for (int nt = 0; nt < 4; ++nt) { a += x[mt][nt]; b += x[mt][nt] * x[mt][nt]; }
#pragma unroll
    for (int r = 0; r < 4; ++r) {
      float s = a[r], s2 = b[r];
#pragma unroll
      for (int off = 1; off < 16; off <<= 1) { s += __shfl_xor(s, off); s2 += __shfl_xor(s2, off); }
      sS[mt][r] = s; sS2[mt][r] = s2;
    }
  }
}

__global__ void __launch_bounds__(512, 2)
bot_main(const int* __restrict__ adj,
         const float* __restrict__ embB, const float* __restrict__ posE,
         const float* __restrict__ pbq, const float* __restrict__ pbk,
         const float* __restrict__ pbv, const float* __restrict__ pbo,
         const float* __restrict__ l1g, const float* __restrict__ l1b,
         const float* __restrict__ l2g, const float* __restrict__ l2b,
         const float* __restrict__ pb1, const float* __restrict__ pb2,
         const bf16* __restrict__ feats, const bf16* __restrict__ embWT,
         const bf16* __restrict__ wqT, const bf16* __restrict__ wkT,
         const bf16* __restrict__ wvT, const bf16* __restrict__ woT,
         const bf16* __restrict__ w1T, const bf16* __restrict__ w2T,
         float* __restrict__ out) {
  __shared__ u8 smem[163840];   // 96KB acts (4 pairs x 24KB) + 2x32KB weights
  const int tid = threadIdx.x;
  const int w = tid >> 6, lane = tid & 63, g = lane >> 4, c = lane & 15;
  const int p = w >> 1, nh = w & 1;   // pair (0..3), N-half
  const int S0 = blockIdx.x * SWG;

  u8* pairb = smem + p * 24576;
  u8* Th = pairb;            // h -> h2
  u8* Tq = pairb + 8192;     // q -> O -> U
  u8* Tk = pairb + 16384;    // k; LN scratch at base in dead windows
  u8* WA = smem + 98304;     // 32KB weight buffer A (Wq, Wv, W1cX)
  u8* WB = smem + 131072;    // 32KB weight buffer B (Wk, Wo, W2cX)
  float* scr = (float*)Tk;

  // transposed mask for swapped-QK^T S^T layout: lane(g,c),r -> (key m=4g+r, query n=c)
  float maskT[4];
#pragma unroll
  for (int r = 0; r < 4; ++r) {
    int m = 4 * g + r;
    maskT[r] = (adj[c * 16 + m] != 0 || c == m) ? 0.f : -1e9f;
  }

  // ---------------- embed (WG-cooperative, transient x0 over act area) ----------------
  {
    float* x0 = (float*)smem;  // [8 samples][2048] = 64KB
    bf16x8 af[2];
#pragma unroll
    for (int ks = 0; ks < 2; ++ks)
      af[ks] = *(const bf16x8*)(feats + (size_t)(S0 + (c & 7)) * 64 + ks * 32 + g * 8);
    f32x4 ea[16] = {};
#pragma unroll
    for (int nt = 0; nt < 16; ++nt)
#pragma unroll
      for (int ks = 0; ks < 2; ++ks) {
        bf16x8 bw = *(const bf16x8*)(embWT + (size_t)(w * 256 + nt * 16 + c) * 64 + ks * 32 + g * 8);
        ea[nt] = mfma32(af[ks], bw, ea[nt]);
      }
    if (g < 2) {
#pragma unroll
      for (int nt = 0; nt < 16; ++nt)
#pragma unroll
        for (int r = 0; r < 4; ++r)
          x0[(4 * g + r) * 2048 + w * 256 + nt * 16 + c] = ea[nt][r];
    }
  }
  __syncthreads();

  f32x4 x[2][4];
  {
    const float* x0 = (const float*)smem;
#pragma unroll
    for (int nt = 0; nt < 4; ++nt)
#pragma unroll
      for (int r = 0; r < 4; ++r) {
        int n = 4 * g + r, d = nh * 64 + nt * 16 + c;
        float eb = embB[n * 128 + d] + posE[n * 128 + d];
#pragma unroll
        for (int mt = 0; mt < 2; ++mt)
          x[mt][nt][r] = x0[(2 * p + mt) * 2048 + n * 128 + d] + eb;
      }
  }
  __syncthreads();

  bf16x8 Ah[2][4], Ah2[2][4], Au[2][4];

  // ---------------- layers: 15 full-weight slots, issue-early lag-1 ----------------
#pragma unroll 1
  for (int l = 0; l < 4; ++l) {
    const u8* Wq_l = (const u8*)(wqT + (size_t)l * 16384);
    const u8* Wk_l = (const u8*)(wkT + (size_t)l * 16384);
    const u8* Wv_l = (const u8*)(wvT + (size_t)l * 16384);
    const u8* Wo_l = (const u8*)(woT + (size_t)l * 16384);
    const u8* W1_l = (const u8*)(w1T + (size_t)l * 65536);
    const u8* W2_l = (const u8*)(w2T + (size_t)l * 65536);

    float sS[2][4], sS2[2][4], mean[2][4], rstd[2][4];
    const f32x4 zz = {0.f, 0.f, 0.f, 0.f};

    // s0: LN1 partials -> scr (Tk base; k dead from prev layer)
    ln_part(x, sS, sS2);
    if (c == 0) {
#pragma unroll
      for (int mt = 0; mt < 2; ++mt)
#pragma unroll
        for (int r = 0; r < 4; ++r) {
          int row = mt * 16 + 4 * g + r;
          scr[(row * 2 + nh) * 2 + 0] = sS[mt][r];
          scr[(row * 2 + nh) * 2 + 1] = sS2[mt][r];
        }
    }
    bar_lg();

    // s1: issue Wq->WA | LN1 combine + h -> Th
    stage32(Wq_l, 256, 0, WA, tid);
#pragma unroll
    for (int mt = 0; mt < 2; ++mt)
#pragma unroll
      for (int r = 0; r < 4; ++r) {
        int row = mt * 16 + 4 * g + r;
        float s = sS[mt][r] + scr[(row * 2 + (1 - nh)) * 2 + 0];
        float s2 = sS2[mt][r] + scr[(row * 2 + (1 - nh)) * 2 + 1];
        float mu = s * (1.f / 128.f);
        float va = s2 * (1.f / 128.f) - mu * mu;
        mean[mt][r] = mu; rstd[mt][r] = rsqrtf(va + 1e-5f);
      }
#pragma unroll
    for (int nt = 0; nt < 4; ++nt) {
      int col = nh * 64 + nt * 16 + c;
      float gg = l1g[l * 128 + col], bb = l1b[l * 128 + col];
#pragma unroll
      for (int mt = 0; mt < 2; ++mt)
#pragma unroll
        for (int r = 0; r < 4; ++r)
          st_row(Th, mt * 16 + 4 * g + r, col,
                 (bf16)((x[mt][nt][r] - mean[mt][r]) * rstd[mt][r] * gg + bb));
    }
    bar_v0();

    f32x4 acc[2][4];
    // s2: issue Wk->WB | loadA(h); Q full (WA) + q epi -> Tq
    stage32(Wk_l, 256, 0, WB, tid);
    loadA_rm(Th, g, c, Ah);
#pragma unroll
    for (int mt = 0; mt < 2; ++mt)
#pragma unroll
      for (int nt = 0; nt < 4; ++nt) acc[mt][nt] = zz;
    gemm_full(WA, Ah, acc, nh, g, c);
    epi_rm<false>(acc, pbq + l * 128, Tq, nh, g, c);
    bar_v0();

    // s3: issue Wv->WA | K full (WB) + k epi -> Tk
    stage32(Wv_l, 256, 0, WA, tid);
#pragma unroll
    for (int mt = 0; mt < 2; ++mt)
#pragma unroll
      for (int nt = 0; nt < 4; ++nt) acc[mt][nt] = zz;
    gemm_full(WB, Ah, acc, nh, g, c);
    epi_rm<false>(acc, pbk + l * 128, Tk, nh, g, c);
    bar_v0();

    // s4: issue Wo->WB | V full (WA) -> Vf; ATTENTION; O -> Tq (over q)
    stage32(Wo_l, 256, 0, WB, tid);
    {
      bf16x8 Vf[2][4];
#pragma unroll
      for (int mt = 0; mt < 2; ++mt)
#pragma unroll
        for (int nt = 0; nt < 4; ++nt) acc[mt][nt] = zz;
      gemm_full(WA, Ah, acc, nh, g, c);
#pragma unroll
      for (int nt = 0; nt < 4; ++nt) {
        float bb = pbv[l * 128 + nh * 64 + nt * 16 + c];
#pragma unroll
        for (int mt = 0; mt < 2; ++mt) {
          f32x4 v;
#pragma unroll
          for (int r = 0; r < 4; ++r) v[r] = acc[mt][nt][r] + bb;
          u32 w0, w1; pack4(v, w0, w1);
          Vf[mt][nt] = Rfrag(w0, w1, g, c);
        }
      }
      const u32 swa = (u32)c << 4;
#pragma unroll
      for (int hh = 0; hh < 4; ++hh) {
        const int gh = nh * 4 + hh;
        bf16x8 qf[2], kf[2];
#pragma unroll
        for (int mt = 0; mt < 2; ++mt) {
          if (g < 2) {
            qf[mt] = *(const bf16x8*)(Tq + (u32)((mt * 16 + c) * 256)
                                         + (((u32)(gh * 32 + g * 16)) ^ swa));
            kf[mt] = *(const bf16x8*)(Tk + (u32)((mt * 16 + c) * 256)
                                         + (((u32)(gh * 32 + g * 16)) ^ swa));
          } else { qf[mt] = zero8(); kf[mt] = zero8(); }
        }
#pragma unroll
        for (int mt = 0; mt < 2; ++mt) {
          f32x4 st = mfma32(kf[mt], qf[mt], zz);    // S^T
          float pr[4];
#pragma unroll
          for (int r = 0; r < 4; ++r) pr[r] = st[r] * 0.25f + maskT[r];
          float mx = fmaxf(fmaxf(pr[0], pr[1]), fmaxf(pr[2], pr[3]));
          mx = fmaxf(mx, __shfl_xor(mx, 16));
          mx = fmaxf(mx, __shfl_xor(mx, 32));
          float sm = 0.f;
#pragma unroll
          for (int r = 0; r < 4; ++r) { pr[r] = __expf(pr[r] - mx); sm += pr[r]; }
          sm += __shfl_xor(sm, 16);
          sm += __shfl_xor(sm, 32);
          float pinv = __fdividef(1.f, sm);
          f32x4 pv;
#pragma unroll
          for (int r = 0; r < 4; ++r) pv[r] = pr[r] * pinv;
          u32 w0, w1; pack4(pv, w0, w1);
          bf16x8 Pf = Rfrag(w0, w1, g, c);
          f32x4 oo = mfma32(Vf[mt][hh], Pf, zz);    // O^T
          pack4(oo, w0, w1);
          bf16x8 Of = Rfrag(w0, w1, g, c);
          if (g < 2)
            *(bf16x8*)(Tq + (u32)((mt * 16 + c) * 256)
                          + (((u32)(gh * 32 + g * 16)) ^ swa)) = Of;
        }
      }
    }
    bar_v0();

    // s5: (no issue) | loadA(O); O-proj (WB) into x; +bo; LN2 partials -> scr
    loadA_rm(Tq, g, c, Ah);
    gemm_full(WB, Ah, x, nh, g, c);
#pragma unroll
    for (int nt = 0; nt < 4; ++nt) {
      float bb = pbo[l * 128 + nh * 64 + nt * 16 + c];
#pragma unroll
      for (int mt = 0; mt < 2; ++mt)
#pragma unroll
        for (int r = 0; r < 4; ++r) x[mt][nt][r] += bb;
    }
    ln_part(x, sS, sS2);
    if (c == 0) {
#pragma unroll
      for (int mt = 0; mt < 2; ++mt)
#pragma unroll
        for (int r = 0; r < 4; ++r) {
          int row = mt * 16 + 4 * g + r;
          scr[(row * 2 + nh) * 2 + 0] = sS[mt][r];
          scr[(row * 2 + nh) * 2 + 1] = sS2[mt][r];
        }
    }
    bar_lg();

    // s6: issue W1c0->WA | LN2 combine + h2 -> Th
    stage32(W1_l, 256, 0, WA, tid);
#pragma unroll
    for (int mt = 0; mt < 2; ++mt)
#pragma unroll
      for (int r = 0; r < 4; ++r) {
        int row = mt * 16 + 4 * g + r;
        float s = sS[mt][r] + scr[(row * 2 + (1 - nh)) * 2 + 0];
        float s2 = sS2[mt][r] + scr[(row * 2 + (1 - nh)) * 2 + 1];
        float mu = s * (1.f / 128.f);
        float va = s2 * (1.f / 128.f) - mu * mu;
        mean[mt][r] = mu; rstd[mt][r] = rsqrtf(va + 1e-5f);
      }
#pragma unroll
    for (int nt = 0; nt < 4; ++nt) {
      int col = nh * 64 + nt * 16 + c;
      float gg = l2g[l * 128 + col], bb = l2b[l * 128 + col];
#pragma unroll
      for (int mt = 0; mt < 2; ++mt)
#pragma unroll
        for (int r = 0; r < 4; ++r)
          st_row(Th, mt * 16 + 4 * g + r, col,
                 (bf16)((x[mt][nt][r] - mean[mt][r]) * rstd[mt][r] * gg + bb));
    }
    bar_v0();

    // ---------------- FFN: 2 slots per fc ----------------
#pragma unroll 1
    for (int fc = 0; fc < 4; ++fc) {
      // sU: issue W2c(fc)->WB | (fc==0: loadA h2); U full (WA) + relu epi -> Tq
      stage32(W2_l, 1024, fc * 256, WB, tid);
      if (fc == 0) loadA_rm(Th, g, c, Ah2);
      f32x4 uacc[2][4];
#pragma unroll
      for (int mt = 0; mt < 2; ++mt)
#pragma unroll
        for (int nt = 0; nt < 4; ++nt) uacc[mt][nt] = zz;
      gemm_full(WA, Ah2, uacc, nh, g, c);
      epi_rm<true>(uacc, pb1 + l * 512 + fc * 128, Tq, nh, g, c);
      bar_v0();
      // sY: issue W1c(fc+1)->WA (fc<3) | loadA(U); Y full (WB) into x
      if (fc < 3) stage32(W1_l + (fc + 1) * 32768, 256, 0, WA, tid);
      loadA_rm(Tq, g, c, Au);
      gemm_full(WB, Au, x, nh, g, c);
      if (fc < 3) bar_v0();
      else {
#pragma unroll
        for (int nt = 0; nt < 4; ++nt) {
          float bb = pb2[l * 128 + nh * 64 + nt * 16 + c];
#pragma unroll
          for (int mt = 0; mt < 2; ++mt)
#pragma unroll
            for (int r = 0; r < 4; ++r) x[mt][nt][r] += bb;
        }
        bar_lg();
      }
    }
  }

  // ---------------- output: LDS bounce -> coalesced nontemporal fp32 stores ----------------
#pragma unroll
  for (int nt = 0; nt < 4; ++nt) {
    int col = nh * 64 + nt * 16 + c;
#pragma unroll
    for (int mt = 0; mt < 2; ++mt)
      *(f32x4*)(pairb + mt * 8192 + col * 64 + g * 16) = x[mt][nt];
  }
  bar_lg();
  {
    const int smp = S0 + 2 * p + nh;
    const u8* src = pairb + nh * 8192;
#pragma unroll
    for (int it = 0; it < 8; ++it) {
      int n = it * 2 + (lane >> 5);
      int slot = lane & 31;
      f32x4 v;
#pragma unroll
      for (int e = 0; e < 4; ++e)
        v[e] = *(const float*)(src + (u32)((slot * 4 + e) * 64 + n * 4));
      __builtin_nontemporal_store(v, (f32x4*)(out + (size_t)smp * 2048 + n * 128 + slot * 4));
    }
  }
}

// ---------------- prep kernels ----------------
__global__ void prep_feats_k(const float* __restrict__ pos, const float* __restrict__ vel,
                             bf16* __restrict__ feats) {
  int i = blockIdx.x * 256 + threadIdx.x;
  if (i >= B_TOT * 64) return;
  int b = i >> 6, k = i & 63;
  float v = (k < 32) ? pos[b * 32 + k] : vel[b * 32 + (k - 32)];
  feats[i] = (bf16)v;
}

// dst[m][cc][rr] = (bf16) src[m][rr][cc]; src is [mats][R][C] fp32
__global__ void prep_tr_k(const float* __restrict__ src, bf16* __restrict__ dst,
                          int R, int C, int total) {
  int i = blockIdx.x * 256 + threadIdx.x;
  if (i >= total) return;
  int rc = R * C;
  int m = i / rc, rem = i % rc;
  int cc = rem / R, rr = rem % R;
  dst[i] = (bf16)src[(size_t)m * rc + rr * C + cc];
}

extern "C" void kernel_launch(void* const* d_in, const int* in_sizes, int n_in,
                              void* d_out, int out_size, void* d_ws, size_t ws_size,
                              hipStream_t stream) {
  const float* jp  = (const float*)d_in[0];
  const float* jv  = (const float*)d_in[1];
  const int*   adj = (const int*)d_in[2];
  const float* eW  = (const float*)d_in[3];
  const float* eB  = (const float*)d_in[4];
  const float* pE  = (const float*)d_in[5];
  const float* Wq  = (const float*)d_in[6];  const float* bq = (const float*)d_in[7];
  const float* Wk  = (const float*)d_in[8];  const float* bk = (const float*)d_in[9];
  const float* Wv  = (const float*)d_in[10]; const float* bv = (const float*)d_in[11];
  const float* Wo  = (const float*)d_in[12]; const float* bo = (const float*)d_in[13];
  const float* g1  = (const float*)d_in[14]; const float* be1 = (const float*)d_in[15];
  const float* g2  = (const float*)d_in[16]; const float* be2 = (const float*)d_in[17];
  const float* W1  = (const float*)d_in[18]; const float* b1 = (const float*)d_in[19];
  const float* W2  = (const float*)d_in[20]; const float* b2 = (const float*)d_in[21];

  bf16* ws    = (bf16*)d_ws;
  bf16* feats = ws;                    // 1048576
  bf16* embWT = ws + 1048576;          // 131072  [16*128 outcol][64 in]
  bf16* wqT   = embWT + 131072;        // 65536   [4][128 out][128 in]
  bf16* wkT   = wqT + 65536;
  bf16* wvT   = wkT + 65536;
  bf16* woT   = wvT + 65536;
  bf16* w1T   = woT + 65536;           // 262144  [4][512 f][128 in]
  bf16* w2T   = w1T + 262144;          // 262144  [4][128 out][512 f]

  prep_feats_k<<<(B_TOT * 64 + 255) / 256, 256, 0, stream>>>(jp, jv, feats);
  prep_tr_k<<<512, 256, 0, stream>>>(eW, embWT, 64, 128, 131072);
  prep_tr_k<<<256, 256, 0, stream>>>(Wq, wqT, 128, 128, 65536);
  prep_tr_k<<<256, 256, 0, stream>>>(Wk, wkT, 128, 128, 65536);
  prep_tr_k<<<256, 256, 0, stream>>>(Wv, wvT, 128, 128, 65536);
  prep_tr_k<<<256, 256, 0, stream>>>(Wo, woT, 128, 128, 65536);
  prep_tr_k<<<1024, 256, 0, stream>>>(W1, w1T, 128, 512, 262144);
  prep_tr_k<<<1024, 256, 0, stream>>>(W2, w2T, 512, 128, 262144);

  bot_main<<<NWGS, 512, 0, stream>>>(adj, eB, pE, bq, bk, bv, bo,
                                     g1, be1, g2, be2, b1, b2,
                                     feats, embWT, wqT, wkT, wvT, woT, w1T, w2T,
                                     (float*)d_out);
}